// Round 7
// baseline (64.829 us; speedup 1.0000x reference)
//
#include <hip/hip_runtime.h>

// BertWordEmbedder: B=64, T=512, H=768, W=256, D=256
// Fully fused: out[b,w,:] = mean_{t in seg(b,w)} hs[b,t,:] @ W + bias
//   prep:  [blocks 0..191]  proj_w [768][256] f32 -> wt [256][768] bf16 (d_ws)
//          [blocks 192..255] bounds[b][w] = lower_bound(wid[b,:], w)    (d_ws)
//   fused: block = (b, 32-word group) x BN=256(all D), BK=64, 12 K-steps.
//          A-tile is POOLED ON THE FLY from hs into LDS (gather, scale, bf16);
//          B streams wt through LDS; next step's loads issue before compute
//          (R6-proven early-issue pattern). hs read exactly once -> 117 MB total.
// Empty words: zero A-row -> out = bias (matches reference).
// ws: [0) wt 393216 | [393216) bounds 65792

#define NB 64
#define NT 512
#define NH 768
#define NW 256
#define ND 256
#define BKS 64
#define NKS (NH / BKS)   // 12

typedef __attribute__((ext_vector_type(8))) short short8;
typedef __attribute__((ext_vector_type(4))) float f32x4;
typedef __attribute__((ext_vector_type(4))) float float4v;
typedef __attribute__((ext_vector_type(4))) unsigned int uint4v;
typedef __attribute__((ext_vector_type(4))) unsigned short ushort4v;

__device__ __forceinline__ unsigned short f2bf(float f) {
    union { float f; unsigned u; } v; v.f = f;
    unsigned r = v.u + 0x7fffu + ((v.u >> 16) & 1u);  // RNE
    return (unsigned short)(r >> 16);
}

// merged prep: wt transpose (192 blocks) + bounds (64 blocks)
__global__ void prep(const float* __restrict__ w, const int* __restrict__ wid,
                     unsigned short* __restrict__ wt, int* __restrict__ bounds) {
    __shared__ float tile[32][33];
    __shared__ int s[NT];
    const int tid = threadIdx.x, n = blockIdx.x;
    if (n < 192) {                               // wt transpose: k0 x n0 32x32 tile
        int tx = tid & 31, ty = tid >> 5;
        int k0 = (n % 24) * 32, n0 = (n / 24) * 32;
        #pragma unroll
        for (int i = 0; i < 4; ++i)
            tile[ty + 8 * i][tx] = w[(size_t)(k0 + ty + 8 * i) * ND + n0 + tx];
        __syncthreads();
        #pragma unroll
        for (int i = 0; i < 4; ++i)
            wt[(size_t)(n0 + ty + 8 * i) * NH + k0 + tx] = f2bf(tile[tx][ty + 8 * i]);
    } else {                                     // bounds for batch b
        int b = n - 192;
        s[tid]       = wid[b * NT + tid];
        s[tid + 256] = wid[b * NT + tid + 256];
        __syncthreads();
        for (int w2 = tid; w2 <= NW; w2 += 256) {
            int lo = 0, hi = NT;
            while (lo < hi) { int m = (lo + hi) >> 1; if (s[m] < w2) lo = m + 1; else hi = m; }
            bounds[b * (NW + 1) + w2] = lo;
        }
    }
}

// fused pool+GEMM. 512 blocks = (b, w-group of 32). 256 thr = 4 waves.
// Wave: 32x64 out tile (2 mt x 4 nt frags). LDS: Asm[32][72], Bsm[256][72].
__global__ __launch_bounds__(256, 2)
void fused(const float* __restrict__ hs, const unsigned short* __restrict__ wt,
           const int* __restrict__ bounds, const float* __restrict__ bias,
           float* __restrict__ out) {
    __shared__ unsigned short Asm[32][72];
    __shared__ unsigned short Bsm[256][72];
    __shared__ int s_bound[33];

    const int tid = threadIdx.x, wave = tid >> 6, lane = tid & 63;
    const int b = blockIdx.x >> 3, w0 = (blockIdx.x & 7) * 32;
    const int cl = lane & 15, kg = lane >> 4;

    if (tid < 33) s_bound[tid] = bounds[b * (NW + 1) + w0 + tid];
    __syncthreads();

    // A-gather: 8 thr/word-row; thread covers k-cols {asub*4..+4} u {asub*4+32..+4}
    const int arow = tid >> 3, asub = tid & 7;
    const int sA = s_bound[arow], eA = s_bound[arow + 1];
    int cnt = eA - sA; if (cnt < 1) cnt = 1;
    const float sc = 1.0f / (float)cnt;
    const float* agp = hs + (size_t)b * NT * NH + asub * 4;
    const unsigned short* bgp = wt + (size_t)tid * NH;   // B: 1 thr/row

    float aacc[8];
    uint4v breg[8];

    f32x4 acc[2][4];
    #pragma unroll
    for (int mt = 0; mt < 2; ++mt)
        #pragma unroll
        for (int nt = 0; nt < 4; ++nt)
            #pragma unroll
            for (int r = 0; r < 4; ++r) acc[mt][nt][r] = 0.f;

#define GATHER_A(k0) {                                                        \
        _Pragma("unroll")                                                     \
        for (int j = 0; j < 8; ++j) aacc[j] = 0.f;                            \
        for (int t = sA; t < eA; ++t) {                                       \
            const float* p = agp + (size_t)t * NH + (k0);                     \
            float4v x0 = *(const float4v*)(p);                                \
            float4v x1 = *(const float4v*)(p + 32);                           \
            aacc[0] += x0[0]; aacc[1] += x0[1]; aacc[2] += x0[2]; aacc[3] += x0[3]; \
            aacc[4] += x1[0]; aacc[5] += x1[1]; aacc[6] += x1[2]; aacc[7] += x1[3]; \
        }                                                                     \
    }
#define GLOAD_B(k0) {                                                         \
        _Pragma("unroll")                                                     \
        for (int i = 0; i < 8; ++i) breg[i] = *(const uint4v*)(bgp + (k0) + i * 8); \
    }
#define SWRITE() {                                                            \
        ushort4v u0, u1;                                                      \
        u0[0] = f2bf(aacc[0] * sc); u0[1] = f2bf(aacc[1] * sc);               \
        u0[2] = f2bf(aacc[2] * sc); u0[3] = f2bf(aacc[3] * sc);               \
        u1[0] = f2bf(aacc[4] * sc); u1[1] = f2bf(aacc[5] * sc);               \
        u1[2] = f2bf(aacc[6] * sc); u1[3] = f2bf(aacc[7] * sc);               \
        *(ushort4v*)&Asm[arow][asub * 4]      = u0;                           \
        *(ushort4v*)&Asm[arow][asub * 4 + 32] = u1;                           \
        _Pragma("unroll")                                                     \
        for (int i = 0; i < 8; ++i) *(uint4v*)&Bsm[tid][i * 8] = breg[i];     \
    }

    GATHER_A(0); GLOAD_B(0);
    for (int ks = 0; ks < NKS; ++ks) {
        SWRITE();
        __syncthreads();
        if (ks + 1 < NKS) { GATHER_A((ks + 1) * BKS); GLOAD_B((ks + 1) * BKS); }
        // compute step ks from LDS (independent of in-flight next-step loads)
        short8 af[2][2], bf[4][2];
        #pragma unroll
        for (int mt = 0; mt < 2; ++mt)
            #pragma unroll
            for (int km = 0; km < 2; ++km)
                af[mt][km] = *(const short8*)&Asm[mt * 16 + cl][km * 32 + kg * 8];
        #pragma unroll
        for (int nt = 0; nt < 4; ++nt)
            #pragma unroll
            for (int km = 0; km < 2; ++km)
                bf[nt][km] = *(const short8*)&Bsm[wave * 64 + nt * 16 + cl][km * 32 + kg * 8];
        #pragma unroll
        for (int mt = 0; mt < 2; ++mt)
            #pragma unroll
            for (int nt = 0; nt < 4; ++nt)
                #pragma unroll
                for (int km = 0; km < 2; ++km)
                    acc[mt][nt] = __builtin_amdgcn_mfma_f32_16x16x32_bf16(af[mt][km], bf[nt][km], acc[mt][nt], 0, 0, 0);
        __syncthreads();
    }
#undef GATHER_A
#undef GLOAD_B
#undef SWRITE

    const int c0 = wave * 64;
    float bv[4];
    #pragma unroll
    for (int nt = 0; nt < 4; ++nt) bv[nt] = bias[c0 + nt * 16 + cl];

    // C/D layout: col=lane&15, row=(lane>>4)*4+r  [proven R1-R6]
    #pragma unroll
    for (int mt = 0; mt < 2; ++mt)
        #pragma unroll
        for (int nt = 0; nt < 4; ++nt)
            #pragma unroll
            for (int r = 0; r < 4; ++r)
                out[((size_t)b * NW + w0 + mt * 16 + kg * 4 + r) * ND + c0 + nt * 16 + cl]
                    = acc[mt][nt][r] + bv[nt];
}

extern "C" void kernel_launch(void* const* d_in, const int* in_sizes, int n_in,
                              void* d_out, int out_size, void* d_ws, size_t ws_size,
                              hipStream_t stream) {
    const float* hs  = (const float*)d_in[0];
    const int*   wid = (const int*)d_in[1];
    const float* pw  = (const float*)d_in[2];
    const float* pb  = (const float*)d_in[3];
    float* out = (float*)d_out;

    unsigned short* wt = (unsigned short*)d_ws;            // 393216 B
    int* bounds        = (int*)((char*)d_ws + 393216);     // 65792 B

    prep<<<256, 256, 0, stream>>>(pw, wid, wt, bounds);
    fused<<<NB * (NW / 32), 256, 0, stream>>>(hs, wt, bounds, pb, out);
}

// Round 8
// 46.284 us; speedup vs baseline: 1.4007x; 1.4007x over previous
//
#include <hip/hip_runtime.h>

// BertWordEmbedder: B=64, T=512, H=768, W=256, D=256
//   prep:        [0..191] proj_w -> wt [256][768] bf16 ; [192..255] bounds
//   pool_pair:   one WAVE per WORD PAIR (2w, 2w+1): their token ranges are
//                adjacent (sorted ids) -> stream one contiguous row range,
//                4-token unroll (12 loads in flight), route rows into the two
//                accumulators by one uniform boundary compare. -> we bf16
//   gemm_lds:    R6-proven LDS-staged MFMA GEMM (unchanged control).
// ws: [0) wt 393216 | [393216) bounds 65792 | [524288) we 25165824

#define NB 64
#define NT 512
#define NH 768
#define NW 256
#define ND 256

typedef __attribute__((ext_vector_type(8))) short short8;
typedef __attribute__((ext_vector_type(4))) float f32x4;
typedef __attribute__((ext_vector_type(4))) float float4v;
typedef __attribute__((ext_vector_type(4))) unsigned int uint4v;
typedef __attribute__((ext_vector_type(4))) unsigned short ushort4v;

__device__ __forceinline__ unsigned short f2bf(float f) {
    union { float f; unsigned u; } v; v.f = f;
    unsigned r = v.u + 0x7fffu + ((v.u >> 16) & 1u);  // RNE
    return (unsigned short)(r >> 16);
}

// merged prep: wt transpose (192 blocks) + bounds (64 blocks)  [R7-proven]
__global__ void prep(const float* __restrict__ w, const int* __restrict__ wid,
                     unsigned short* __restrict__ wt, int* __restrict__ bounds) {
    __shared__ float tile[32][33];
    __shared__ int s[NT];
    const int tid = threadIdx.x, n = blockIdx.x;
    if (n < 192) {
        int tx = tid & 31, ty = tid >> 5;
        int k0 = (n % 24) * 32, n0 = (n / 24) * 32;
        #pragma unroll
        for (int i = 0; i < 4; ++i)
            tile[ty + 8 * i][tx] = w[(size_t)(k0 + ty + 8 * i) * ND + n0 + tx];
        __syncthreads();
        #pragma unroll
        for (int i = 0; i < 4; ++i)
            wt[(size_t)(n0 + ty + 8 * i) * NH + k0 + tx] = f2bf(tile[tx][ty + 8 * i]);
    } else {
        int b = n - 192;
        s[tid]       = wid[b * NT + tid];
        s[tid + 256] = wid[b * NT + tid + 256];
        __syncthreads();
        for (int w2 = tid; w2 <= NW; w2 += 256) {
            int lo = 0, hi = NT;
            while (lo < hi) { int m = (lo + hi) >> 1; if (s[m] < w2) lo = m + 1; else hi = m; }
            bounds[b * (NW + 1) + w2] = lo;
        }
    }
}

// one wave per word PAIR: contiguous token range [s,e), boundary m splits it.
// 4-token unroll -> 12x1KB loads in flight; cndmask routing (uniform cond).
__global__ __launch_bounds__(256)
void pool_pair(const float* __restrict__ hs, const int* __restrict__ bounds,
               unsigned short* __restrict__ we) {
    const int wave = threadIdx.x >> 6, lane = threadIdx.x & 63;
    const int idx = blockIdx.x * 4 + wave;          // 0..8191 = (b, wordpair j)
    const int b = idx >> 7, j = idx & 127;

    const int* bp = bounds + b * (NW + 1) + 2 * j;
    int s = __builtin_amdgcn_readfirstlane(bp[0]);
    int m = __builtin_amdgcn_readfirstlane(bp[1]);
    int e = __builtin_amdgcn_readfirstlane(bp[2]);

    const float* base = hs + (size_t)b * NT * NH + lane * 4;
    float4v a0c0 = {0,0,0,0}, a0c1 = {0,0,0,0}, a0c2 = {0,0,0,0};
    float4v a1c0 = {0,0,0,0}, a1c1 = {0,0,0,0}, a1c2 = {0,0,0,0};

#define ROUTE(t, v0, v1, v2) {                                                \
        if ((t) < m) {                                                        \
            _Pragma("unroll") for (int q = 0; q < 4; ++q) {                   \
                a0c0[q] += (v0)[q]; a0c1[q] += (v1)[q]; a0c2[q] += (v2)[q]; } \
        } else {                                                              \
            _Pragma("unroll") for (int q = 0; q < 4; ++q) {                   \
                a1c0[q] += (v0)[q]; a1c1[q] += (v1)[q]; a1c2[q] += (v2)[q]; } \
        }                                                                     \
    }

    int t = s;
    for (; t + 4 <= e; t += 4) {                    // 12 loads in flight
        float4v v[4][3];
        #pragma unroll
        for (int u = 0; u < 4; ++u) {
            const float* p = base + (size_t)(t + u) * NH;
            v[u][0] = *(const float4v*)(p);
            v[u][1] = *(const float4v*)(p + 256);
            v[u][2] = *(const float4v*)(p + 512);
        }
        #pragma unroll
        for (int u = 0; u < 4; ++u) ROUTE(t + u, v[u][0], v[u][1], v[u][2]);
    }
    for (; t < e; ++t) {
        const float* p = base + (size_t)t * NH;
        float4v v0 = *(const float4v*)(p);
        float4v v1 = *(const float4v*)(p + 256);
        float4v v2 = *(const float4v*)(p + 512);
        ROUTE(t, v0, v1, v2);
    }
#undef ROUTE

    int c0 = m - s; if (c0 < 1) c0 = 1;
    int c1 = e - m; if (c1 < 1) c1 = 1;
    const float s0 = 1.0f / (float)c0, s1 = 1.0f / (float)c1;

    unsigned short* d0 = we + (size_t)(2 * idx) * NH + lane * 4;
    unsigned short* d1 = d0 + NH;
    ushort4v u;
    #pragma unroll
    for (int q = 0; q < 4; ++q) u[q] = f2bf(a0c0[q] * s0);
    *(ushort4v*)(d0) = u;
    #pragma unroll
    for (int q = 0; q < 4; ++q) u[q] = f2bf(a0c1[q] * s0);
    *(ushort4v*)(d0 + 256) = u;
    #pragma unroll
    for (int q = 0; q < 4; ++q) u[q] = f2bf(a0c2[q] * s0);
    *(ushort4v*)(d0 + 512) = u;
    #pragma unroll
    for (int q = 0; q < 4; ++q) u[q] = f2bf(a1c0[q] * s1);
    *(ushort4v*)(d1) = u;
    #pragma unroll
    for (int q = 0; q < 4; ++q) u[q] = f2bf(a1c1[q] * s1);
    *(ushort4v*)(d1 + 256) = u;
    #pragma unroll
    for (int q = 0; q < 4; ++q) u[q] = f2bf(a1c2[q] * s1);
    *(ushort4v*)(d1 + 512) = u;
}

// out[16384x256] = we @ wt^T + bias. R6-proven LDS-staged GEMM (unchanged).
__global__ __launch_bounds__(256)
void gemm_lds(const unsigned short* __restrict__ we, const unsigned short* __restrict__ wt,
              const float* __restrict__ bias, float* __restrict__ out) {
    __shared__ unsigned short Asm[128][72];
    __shared__ unsigned short Bsm[64][72];

    const int tid = threadIdx.x, wave = tid >> 6, lane = tid & 63;
    const int cl = lane & 15, kg = lane >> 4;
    const size_t r0 = (size_t)blockIdx.x * 128;
    const int c0 = blockIdx.y * 64;
    const int wm0 = (wave >> 1) * 64, wn0 = (wave & 1) * 32;

    const int arow = tid >> 1, ah = tid & 1;
    const int brow = tid >> 2, bq = tid & 3;
    const unsigned short* agp = we + (r0 + arow) * NH;
    const unsigned short* bgp = wt + (size_t)(c0 + brow) * NH;

    uint4v sA0[4], sB0[2], sA1[4], sB1[2];

    auto gload = [&](uint4v* sA, uint4v* sB, int k0e) {
        #pragma unroll
        for (int i = 0; i < 4; ++i)
            sA[i] = *(const uint4v*)(agp + k0e + (ah + 2 * i) * 8);
        #pragma unroll
        for (int i = 0; i < 2; ++i)
            sB[i] = *(const uint4v*)(bgp + k0e + (bq + 4 * i) * 8);
    };
    auto swrite = [&](uint4v* sA, uint4v* sB) {
        #pragma unroll
        for (int i = 0; i < 4; ++i)
            *(uint4v*)&Asm[arow][(ah + 2 * i) * 8] = sA[i];
        #pragma unroll
        for (int i = 0; i < 2; ++i)
            *(uint4v*)&Bsm[brow][(bq + 4 * i) * 8] = sB[i];
    };

    f32x4 acc[4][2];
    #pragma unroll
    for (int mt = 0; mt < 4; ++mt)
        #pragma unroll
        for (int nt = 0; nt < 2; ++nt)
            #pragma unroll
            for (int r = 0; r < 4; ++r) acc[mt][nt][r] = 0.f;

    auto compute = [&]() {
        short8 af[4][2], bf[2][2];
        #pragma unroll
        for (int mt = 0; mt < 4; ++mt)
            #pragma unroll
            for (int km = 0; km < 2; ++km)
                af[mt][km] = *(const short8*)&Asm[wm0 + mt * 16 + cl][km * 32 + kg * 8];
        #pragma unroll
        for (int nt = 0; nt < 2; ++nt)
            #pragma unroll
            for (int km = 0; km < 2; ++km)
                bf[nt][km] = *(const short8*)&Bsm[wn0 + nt * 16 + cl][km * 32 + kg * 8];
        #pragma unroll
        for (int mt = 0; mt < 4; ++mt)
            #pragma unroll
            for (int nt = 0; nt < 2; ++nt)
                #pragma unroll
                for (int km = 0; km < 2; ++km)
                    acc[mt][nt] = __builtin_amdgcn_mfma_f32_16x16x32_bf16(af[mt][km], bf[nt][km], acc[mt][nt], 0, 0, 0);
    };

    gload(sA0, sB0, 0);
    for (int ks = 0; ks < 12; ks += 2) {
        swrite(sA0, sB0);
        __syncthreads();
        gload(sA1, sB1, (ks + 1) * 64);
        compute();
        __syncthreads();
        swrite(sA1, sB1);
        __syncthreads();
        if (ks + 2 < 12) gload(sA0, sB0, (ks + 2) * 64);
        compute();
        __syncthreads();
    }

    float bv[2];
    bv[0] = bias[c0 + wn0 + cl];
    bv[1] = bias[c0 + wn0 + 16 + cl];

    #pragma unroll
    for (int mt = 0; mt < 4; ++mt)
        #pragma unroll
        for (int nt = 0; nt < 2; ++nt)
            #pragma unroll
            for (int r = 0; r < 4; ++r)
                out[(r0 + wm0 + mt * 16 + kg * 4 + r) * ND + c0 + wn0 + nt * 16 + cl]
                    = acc[mt][nt][r] + bv[nt];
}

extern "C" void kernel_launch(void* const* d_in, const int* in_sizes, int n_in,
                              void* d_out, int out_size, void* d_ws, size_t ws_size,
                              hipStream_t stream) {
    const float* hs  = (const float*)d_in[0];
    const int*   wid = (const int*)d_in[1];
    const float* pw  = (const float*)d_in[2];
    const float* pb  = (const float*)d_in[3];
    float* out = (float*)d_out;

    unsigned short* wt = (unsigned short*)d_ws;                      // 393216 B
    int* bounds        = (int*)((char*)d_ws + 393216);               // 65792 B
    unsigned short* we = (unsigned short*)((char*)d_ws + 524288);    // 25165824 B

    prep<<<256, 256, 0, stream>>>(pw, wid, wt, bounds);
    pool_pair<<<(NB * NW / 2) / 4, 256, 0, stream>>>(hs, bounds, we);
    dim3 gg(NB * NW / 128, ND / 64);
    gemm_lds<<<gg, 256, 0, stream>>>(we, wt, pb, out);
}